// Round 2
// baseline (687.235 us; speedup 1.0000x reference)
//
#include <hip/hip_runtime.h>

// ---------------------------------------------------------------------------
// TT linear layer (ALL I/O fp32 — reference dtype; R0's NaN came from
// misreading fp32 as bf16):  out[8192,4096] = x @ G^T + bias,
// G[4096,4096] materialized from 3 TT cores.
//
// build_g: fp32 cores -> bf16 G in d_ws (32 MB), factored contraction.
// gemm:    bf16 MFMA 16x16x32, 128x128 tile, BK=32.
//          B (G, bf16) staged via async global_load_lds width-16.
//          A (x, fp32) staged via coalesced float4 loads -> truncate-pack
//          bf16 -> lane-contiguous ds_write_b128 (conflict-free).
//          fp32 accumulate, fp32 bias + fp32 stores in epilogue.
// ---------------------------------------------------------------------------

typedef short bf16x8 __attribute__((ext_vector_type(8)));
typedef float f32x4 __attribute__((ext_vector_type(4)));

__device__ __forceinline__ unsigned short f2bf_rne(float f) {
  union { float f; unsigned int i; } v;
  v.f = f;
  unsigned int r = v.i + 0x7FFFu + ((v.i >> 16) & 1u);
  return (unsigned short)(r >> 16);
}

// pack two fp32 -> two bf16 (truncate toward zero; rel err <= 2^-8, sign-
// symmetric so dot-product error random-walks: ~0.006 sigma vs 0.121 budget)
__device__ __forceinline__ unsigned int pk2bf(float lo, float hi) {
  union { float f; unsigned int u; } a, b;
  a.f = lo; b.f = hi;
  return (b.u & 0xFFFF0000u) | (a.u >> 16);
}

__device__ __forceinline__ void gl2lds16(const void* g, void* l) {
  __builtin_amdgcn_global_load_lds(
      (__attribute__((address_space(1))) void*)g,
      (__attribute__((address_space(3))) void*)l, 16u, 0, 0u);
}

// ---------------------------------------------------------------------------
// G[row=(i,j,k)][col=(n,m,o)] = sum_{b,c} core0[0,i,n,b] core1[b,j,m,c]
//                                          core2[c,k,o,0]
// one block per (i,j,k) row; factored via H[n,m,c] = sum_b core0*core1.
// ---------------------------------------------------------------------------
__global__ __launch_bounds__(256) void build_g(
    const float* __restrict__ core0,   // [1,16,16,16]  (i,n,b)
    const float* __restrict__ core1,   // [16,16,16,16] (b,j,m,c)
    const float* __restrict__ core2,   // [16,16,16,1]  (c,k,o)
    unsigned short* __restrict__ G) {  // [4096,4096] bf16
  __shared__ float c0[256];   // [n][b]
  __shared__ float c1[4096];  // [b][m][c]  (j slice)
  __shared__ float c2[4096];  // [c][p][o]  (full)
  __shared__ float h[4096];   // [n][m][c]
  const int t = threadIdx.x;
  const int blk = blockIdx.x;
  const int i = blk >> 8, j = (blk >> 4) & 15, p = blk & 15;

  c0[t] = core0[i * 256 + t];
#pragma unroll
  for (int q = 0; q < 16; q++) {
    int idx = q * 256 + t;
    int bb = idx >> 8, mc = idx & 255;
    c1[idx] = core1[bb * 4096 + j * 256 + mc];
    c2[idx] = core2[idx];
  }
  __syncthreads();

  {
    const int n = t >> 4, m = t & 15;
#pragma unroll
    for (int c = 0; c < 16; c++) {
      float s = 0.f;
#pragma unroll
      for (int bb = 0; bb < 16; bb++)
        s += c0[n * 16 + bb] * c1[bb * 256 + m * 16 + c];
      h[t * 16 + c] = s;
    }
  }
  __syncthreads();

  const size_t rowbase = (size_t)(i * 256 + j * 16 + p) * 4096;
  const int m = t >> 4, o = t & 15;
#pragma unroll
  for (int chunk = 0; chunk < 16; chunk++) {
    float s = 0.f;
#pragma unroll
    for (int c = 0; c < 16; c++)
      s += h[(chunk * 16 + m) * 16 + c] * c2[c * 256 + p * 16 + o];
    G[rowbase + chunk * 256 + t] = f2bf_rne(s);
  }
}

// ---------------------------------------------------------------------------
// GEMM: C[M,N] = A[M,K] (fp32) * Bt[N,K]^T (bf16) + bias, fp32 out.
// ---------------------------------------------------------------------------
constexpr int Mdim = 8192, Ndim = 4096, Kdim = 4096;

__global__ __launch_bounds__(256, 3) void gemm_bt(
    const float* __restrict__ A,              // [M,K] fp32
    const unsigned short* __restrict__ Bt,    // [N,K] bf16
    const float* __restrict__ bias,           // [N]   fp32
    float* __restrict__ C) {                  // [M,N] fp32
  __shared__ __align__(16) unsigned short lA[128 * 32];
  __shared__ __align__(16) unsigned short lB[128 * 32];
  const int tid = threadIdx.x, lane = tid & 63, wave = tid >> 6;
  const int bm0 = blockIdx.y * 128, bn0 = blockIdx.x * 128;
  const int wm = wave >> 1, wn = wave & 1;

  // --- B staging (async, bf16): wave w rows [w*32, w*32+32), lane ->
  // (row = lane/4, col8 = (lane%4)*8); LDS dst = wave base + lane*16 B.
  const int srow = lane >> 2, scol = (lane & 3) * 8;
  const unsigned short* Bg =
      Bt + (size_t)(bn0 + wave * 32 + srow) * Kdim + scol;
  unsigned short* lBp = &lB[wave * 32 * 32 + lane * 8];

  // --- A staging (fp32->bf16): thread covers rows arow and arow+64 at
  // k-offset acol..acol+8. LDS writes are lane-contiguous 16 B (no bank
  // conflicts on ds_write_b128).
  const int arow = wave * 16 + (lane >> 2);  // 0..63
  const int acol = (lane & 3) * 8;           // 0,8,16,24
  const float* Ag0 = A + (size_t)(bm0 + arow) * Kdim + acol;
  const float* Ag1 = Ag0 + (size_t)64 * Kdim;
  uint4* lAw0 = (uint4*)&lA[tid * 8];         // rows 0..63 region
  uint4* lAw1 = (uint4*)&lA[2048 + tid * 8];  // rows 64..127 region

  f32x4 acc[4][4];
  const f32x4 zero = {0.f, 0.f, 0.f, 0.f};
#pragma unroll
  for (int a = 0; a < 4; a++)
#pragma unroll
    for (int b = 0; b < 4; b++) acc[a][b] = zero;

  const int row = lane & 15, quad = lane >> 4;

  for (int k0 = 0; k0 < Kdim; k0 += 32) {
    __syncthreads();
    // async B first so DMA overlaps the A convert work
    gl2lds16(Bg + k0, lBp);
    gl2lds16(Bg + k0 + 16 * Kdim, lBp + 16 * 32);

    float4 a0 = *(const float4*)(Ag0 + k0);
    float4 a1 = *(const float4*)(Ag0 + k0 + 4);
    float4 a2 = *(const float4*)(Ag1 + k0);
    float4 a3 = *(const float4*)(Ag1 + k0 + 4);
    uint4 w0 = {pk2bf(a0.x, a0.y), pk2bf(a0.z, a0.w),
                pk2bf(a1.x, a1.y), pk2bf(a1.z, a1.w)};
    uint4 w1 = {pk2bf(a2.x, a2.y), pk2bf(a2.z, a2.w),
                pk2bf(a3.x, a3.y), pk2bf(a3.z, a3.w)};
    *lAw0 = w0;
    *lAw1 = w1;
    __syncthreads();  // compiler drains vmcnt+lgkmcnt before s_barrier

    bf16x8 af[4], bfv[4];
#pragma unroll
    for (int mi = 0; mi < 4; mi++)
      af[mi] = *(const bf16x8*)&lA[(wm * 64 + mi * 16 + row) * 32 + quad * 8];
#pragma unroll
    for (int ni = 0; ni < 4; ni++)
      bfv[ni] = *(const bf16x8*)&lB[(wn * 64 + ni * 16 + row) * 32 + quad * 8];
#pragma unroll
    for (int mi = 0; mi < 4; mi++)
#pragma unroll
      for (int ni = 0; ni < 4; ni++)
        acc[mi][ni] = __builtin_amdgcn_mfma_f32_16x16x32_bf16(
            af[mi], bfv[ni], acc[mi][ni], 0, 0, 0);
  }

  // epilogue: C/D layout col = lane&15, row = quad*4 + r (m89-verified)
#pragma unroll
  for (int ni = 0; ni < 4; ni++) {
    const int n = bn0 + wn * 64 + ni * 16 + row;
    const float bv = bias[n];
#pragma unroll
    for (int mi = 0; mi < 4; mi++) {
      const int mbase = bm0 + wm * 64 + mi * 16 + quad * 4;
#pragma unroll
      for (int r = 0; r < 4; r++)
        C[(size_t)(mbase + r) * Ndim + n] = acc[mi][ni][r] + bv;
    }
  }
}

// ---------------------------------------------------------------------------
extern "C" void kernel_launch(void* const* d_in, const int* in_sizes, int n_in,
                              void* d_out, int out_size, void* d_ws,
                              size_t ws_size, hipStream_t stream) {
  const float* x = (const float*)d_in[0];      // [4,2048,4096] -> [8192,4096]
  const float* core0 = (const float*)d_in[1];  // [1,16,16,16]
  const float* core1 = (const float*)d_in[2];  // [16,16,16,16]
  const float* core2 = (const float*)d_in[3];  // [16,16,16,1]
  const float* bias = (const float*)d_in[4];   // [4096]
  float* out = (float*)d_out;                  // [8192,4096]
  unsigned short* G = (unsigned short*)d_ws;   // [4096,4096] bf16 = 32 MB

  build_g<<<4096, 256, 0, stream>>>(core0, core1, core2, G);
  dim3 grid(Ndim / 128, Mdim / 128);  // 32 x 64
  gemm_bt<<<grid, 256, 0, stream>>>(x, G, bias, out);
}

// Round 3
// 582.735 us; speedup vs baseline: 1.1793x; 1.1793x over previous
//
#include <hip/hip_runtime.h>

// ---------------------------------------------------------------------------
// TT linear layer, all I/O fp32: out[8192,4096] = x @ G^T + bias.
// R2: pre-convert x -> bf16 (64 MB in d_ws) so the GEMM is the pure m97
// structure: BOTH operands staged via async global_load_lds width-16 —
// removes the VMEM->VALU->ds_write round-trip that left R1 60% idle
// (MfmaUtil 24%, VALUBusy 15%).
//   d_ws layout: [0,32MB) G bf16 [4096,4096]; [32MB,96MB) x bf16 [8192,4096].
// ---------------------------------------------------------------------------

typedef short bf16x8 __attribute__((ext_vector_type(8)));
typedef float f32x4 __attribute__((ext_vector_type(4)));

__device__ __forceinline__ unsigned short f2bf_rne(float f) {
  union { float f; unsigned int i; } v;
  v.f = f;
  unsigned int r = v.i + 0x7FFFu + ((v.i >> 16) & 1u);
  return (unsigned short)(r >> 16);
}

__device__ __forceinline__ unsigned int pk2bf_rne(float lo, float hi) {
  return (unsigned int)f2bf_rne(lo) | ((unsigned int)f2bf_rne(hi) << 16);
}

__device__ __forceinline__ unsigned int pk2bf_trunc(float lo, float hi) {
  union { float f; unsigned int u; } a, b;
  a.f = lo; b.f = hi;
  return (b.u & 0xFFFF0000u) | (a.u >> 16);
}

__device__ __forceinline__ void gl2lds16(const void* g, void* l) {
  __builtin_amdgcn_global_load_lds(
      (__attribute__((address_space(1))) void*)g,
      (__attribute__((address_space(3))) void*)l, 16u, 0, 0u);
}

// ---------------------------------------------------------------------------
// x fp32 -> bf16 (RNE). 33.5M elems, 8 per thread: read 2 float4, write uint4.
// ---------------------------------------------------------------------------
__global__ __launch_bounds__(256) void cvt_x(const float* __restrict__ x,
                                             unsigned short* __restrict__ xb) {
  const size_t t = (size_t)blockIdx.x * 256 + threadIdx.x;
  const float4 a0 = *(const float4*)(x + t * 8);
  const float4 a1 = *(const float4*)(x + t * 8 + 4);
  uint4 w = {pk2bf_rne(a0.x, a0.y), pk2bf_rne(a0.z, a0.w),
             pk2bf_rne(a1.x, a1.y), pk2bf_rne(a1.z, a1.w)};
  *(uint4*)(xb + t * 8) = w;
}

// ---------------------------------------------------------------------------
// G[(i,j,p)][(n,m,o)] = sum_{b,c} core0[0,i,n,b] core1[b,j,m,c] core2[c,p,o,0]
// ---------------------------------------------------------------------------
__global__ __launch_bounds__(256) void build_g(
    const float* __restrict__ core0, const float* __restrict__ core1,
    const float* __restrict__ core2, unsigned short* __restrict__ G) {
  __shared__ float c0[256];   // [n][b]
  __shared__ float c1[4096];  // [b][m][c]  (j slice)
  __shared__ float c2[4096];  // [c][p][o]
  __shared__ float h[4096];   // [n][m][c]
  const int t = threadIdx.x;
  const int blk = blockIdx.x;
  const int i = blk >> 8, j = (blk >> 4) & 15, p = blk & 15;

  c0[t] = core0[i * 256 + t];
#pragma unroll
  for (int q = 0; q < 16; q++) {
    int idx = q * 256 + t;
    int bb = idx >> 8, mc = idx & 255;
    c1[idx] = core1[bb * 4096 + j * 256 + mc];
    c2[idx] = core2[idx];
  }
  __syncthreads();
  {
    const int n = t >> 4, m = t & 15;
#pragma unroll
    for (int c = 0; c < 16; c++) {
      float s = 0.f;
#pragma unroll
      for (int bb = 0; bb < 16; bb++)
        s += c0[n * 16 + bb] * c1[bb * 256 + m * 16 + c];
      h[t * 16 + c] = s;
    }
  }
  __syncthreads();
  const size_t rowbase = (size_t)(i * 256 + j * 16 + p) * 4096;
  const int m = t >> 4, o = t & 15;
#pragma unroll
  for (int chunk = 0; chunk < 16; chunk++) {
    float s = 0.f;
#pragma unroll
    for (int c = 0; c < 16; c++)
      s += h[(chunk * 16 + m) * 16 + c] * c2[c * 256 + p * 16 + o];
    G[rowbase + chunk * 256 + t] = f2bf_rne(s);
  }
}

// ---------------------------------------------------------------------------
// GEMM (m97 structure): C[M,N] = A[M,K] * Bt[N,K]^T + bias.
// A, Bt bf16 (both async-DMA staged), C fp32, fp32 accumulate.
// ---------------------------------------------------------------------------
constexpr int Mdim = 8192, Ndim = 4096, Kdim = 4096;

__global__ __launch_bounds__(256, 4) void gemm_bb(
    const unsigned short* __restrict__ A,     // [M,K] bf16
    const unsigned short* __restrict__ Bt,    // [N,K] bf16
    const float* __restrict__ bias,           // [N]
    float* __restrict__ C) {                  // [M,N] fp32
  __shared__ __align__(16) unsigned short lA[128 * 32];
  __shared__ __align__(16) unsigned short lB[128 * 32];
  const int tid = threadIdx.x, lane = tid & 63, wave = tid >> 6;
  const int bm0 = blockIdx.y * 128, bn0 = blockIdx.x * 128;
  const int wm = wave >> 1, wn = wave & 1;

  // staging: wave w covers tile rows [w*32, w*32+32) in two 16-row issues;
  // lane -> (row = lane/4, col8 = (lane%4)*8). LDS dst = wave base + lane*16B.
  const int srow = lane >> 2, scol = (lane & 3) * 8;
  const unsigned short* Ag = A + (size_t)(bm0 + wave * 32 + srow) * Kdim + scol;
  const unsigned short* Bg = Bt + (size_t)(bn0 + wave * 32 + srow) * Kdim + scol;
  unsigned short* lAp = &lA[wave * 32 * 32 + lane * 8];
  unsigned short* lBp = &lB[wave * 32 * 32 + lane * 8];

  f32x4 acc[4][4];
  const f32x4 zero = {0.f, 0.f, 0.f, 0.f};
#pragma unroll
  for (int a = 0; a < 4; a++)
#pragma unroll
    for (int b = 0; b < 4; b++) acc[a][b] = zero;

  const int row = lane & 15, quad = lane >> 4;

  for (int k0 = 0; k0 < Kdim; k0 += 32) {
    __syncthreads();
    gl2lds16(Ag + k0, lAp);
    gl2lds16(Ag + k0 + 16 * Kdim, lAp + 16 * 32);
    gl2lds16(Bg + k0, lBp);
    gl2lds16(Bg + k0 + 16 * Kdim, lBp + 16 * 32);
    __syncthreads();  // compiler drains vmcnt before s_barrier

    bf16x8 af[4], bfv[4];
#pragma unroll
    for (int mi = 0; mi < 4; mi++)
      af[mi] = *(const bf16x8*)&lA[(wm * 64 + mi * 16 + row) * 32 + quad * 8];
#pragma unroll
    for (int ni = 0; ni < 4; ni++)
      bfv[ni] = *(const bf16x8*)&lB[(wn * 64 + ni * 16 + row) * 32 + quad * 8];
#pragma unroll
    for (int mi = 0; mi < 4; mi++)
#pragma unroll
      for (int ni = 0; ni < 4; ni++)
        acc[mi][ni] = __builtin_amdgcn_mfma_f32_16x16x32_bf16(
            af[mi], bfv[ni], acc[mi][ni], 0, 0, 0);
  }

  // epilogue: C/D layout col = lane&15, row = quad*4 + r (m89-verified)
#pragma unroll
  for (int ni = 0; ni < 4; ni++) {
    const int n = bn0 + wn * 64 + ni * 16 + row;
    const float bv = bias[n];
#pragma unroll
    for (int mi = 0; mi < 4; mi++) {
      const int mbase = bm0 + wm * 64 + mi * 16 + quad * 4;
#pragma unroll
      for (int r = 0; r < 4; r++)
        C[(size_t)(mbase + r) * Ndim + n] = acc[mi][ni][r] + bv;
    }
  }
}

// ---------------------------------------------------------------------------
// Fallback GEMM (R1 path, used only if ws_size < 96 MB): A fp32 packed
// in-loop. Known-good: passed R1 at 500 µs.
// ---------------------------------------------------------------------------
__global__ __launch_bounds__(256, 3) void gemm_pack(
    const float* __restrict__ A, const unsigned short* __restrict__ Bt,
    const float* __restrict__ bias, float* __restrict__ C) {
  __shared__ __align__(16) unsigned short lA[128 * 32];
  __shared__ __align__(16) unsigned short lB[128 * 32];
  const int tid = threadIdx.x, lane = tid & 63, wave = tid >> 6;
  const int bm0 = blockIdx.y * 128, bn0 = blockIdx.x * 128;
  const int wm = wave >> 1, wn = wave & 1;
  const int srow = lane >> 2, scol = (lane & 3) * 8;
  const unsigned short* Bg = Bt + (size_t)(bn0 + wave * 32 + srow) * Kdim + scol;
  unsigned short* lBp = &lB[wave * 32 * 32 + lane * 8];
  const int arow = wave * 16 + (lane >> 2);
  const int acol = (lane & 3) * 8;
  const float* Ag0 = A + (size_t)(bm0 + arow) * Kdim + acol;
  const float* Ag1 = Ag0 + (size_t)64 * Kdim;
  uint4* lAw0 = (uint4*)&lA[tid * 8];
  uint4* lAw1 = (uint4*)&lA[2048 + tid * 8];

  f32x4 acc[4][4];
  const f32x4 zero = {0.f, 0.f, 0.f, 0.f};
#pragma unroll
  for (int a = 0; a < 4; a++)
#pragma unroll
    for (int b = 0; b < 4; b++) acc[a][b] = zero;
  const int row = lane & 15, quad = lane >> 4;

  for (int k0 = 0; k0 < Kdim; k0 += 32) {
    __syncthreads();
    gl2lds16(Bg + k0, lBp);
    gl2lds16(Bg + k0 + 16 * Kdim, lBp + 16 * 32);
    float4 a0 = *(const float4*)(Ag0 + k0);
    float4 a1 = *(const float4*)(Ag0 + k0 + 4);
    float4 a2 = *(const float4*)(Ag1 + k0);
    float4 a3 = *(const float4*)(Ag1 + k0 + 4);
    uint4 w0 = {pk2bf_trunc(a0.x, a0.y), pk2bf_trunc(a0.z, a0.w),
                pk2bf_trunc(a1.x, a1.y), pk2bf_trunc(a1.z, a1.w)};
    uint4 w1 = {pk2bf_trunc(a2.x, a2.y), pk2bf_trunc(a2.z, a2.w),
                pk2bf_trunc(a3.x, a3.y), pk2bf_trunc(a3.z, a3.w)};
    *lAw0 = w0;
    *lAw1 = w1;
    __syncthreads();

    bf16x8 af[4], bfv[4];
#pragma unroll
    for (int mi = 0; mi < 4; mi++)
      af[mi] = *(const bf16x8*)&lA[(wm * 64 + mi * 16 + row) * 32 + quad * 8];
#pragma unroll
    for (int ni = 0; ni < 4; ni++)
      bfv[ni] = *(const bf16x8*)&lB[(wn * 64 + ni * 16 + row) * 32 + quad * 8];
#pragma unroll
    for (int mi = 0; mi < 4; mi++)
#pragma unroll
      for (int ni = 0; ni < 4; ni++)
        acc[mi][ni] = __builtin_amdgcn_mfma_f32_16x16x32_bf16(
            af[mi], bfv[ni], acc[mi][ni], 0, 0, 0);
  }
#pragma unroll
  for (int ni = 0; ni < 4; ni++) {
    const int n = bn0 + wn * 64 + ni * 16 + row;
    const float bv = bias[n];
#pragma unroll
    for (int mi = 0; mi < 4; mi++) {
      const int mbase = bm0 + wm * 64 + mi * 16 + quad * 4;
#pragma unroll
      for (int r = 0; r < 4; r++)
        C[(size_t)(mbase + r) * Ndim + n] = acc[mi][ni][r] + bv;
    }
  }
}

// ---------------------------------------------------------------------------
extern "C" void kernel_launch(void* const* d_in, const int* in_sizes, int n_in,
                              void* d_out, int out_size, void* d_ws,
                              size_t ws_size, hipStream_t stream) {
  const float* x = (const float*)d_in[0];
  const float* core0 = (const float*)d_in[1];
  const float* core1 = (const float*)d_in[2];
  const float* core2 = (const float*)d_in[3];
  const float* bias = (const float*)d_in[4];
  float* out = (float*)d_out;

  unsigned short* G = (unsigned short*)d_ws;  // 32 MB
  const size_t G_BYTES = (size_t)4096 * 4096 * 2;
  const size_t X_BYTES = (size_t)Mdim * Kdim * 2;  // 64 MB

  build_g<<<4096, 256, 0, stream>>>(core0, core1, core2, G);
  dim3 grid(Ndim / 128, Mdim / 128);  // 32 x 64 = 2048 blocks

  if (ws_size >= G_BYTES + X_BYTES) {
    unsigned short* Xb = (unsigned short*)((char*)d_ws + G_BYTES);
    cvt_x<<<(Mdim * Kdim) / (256 * 8), 256, 0, stream>>>(x, Xb);
    gemm_bb<<<grid, 256, 0, stream>>>(Xb, G, bias, out);
  } else {
    gemm_pack<<<grid, 256, 0, stream>>>(x, G, bias, out);
  }
}

// Round 4
// 533.243 us; speedup vs baseline: 1.2888x; 1.0928x over previous
//
#include <hip/hip_runtime.h>

// ---------------------------------------------------------------------------
// TT linear layer, all I/O fp32: out[8192,4096] = x @ G^T + bias.
// R3: build_g rewritten — R2 profile showed ~208 us hidden in build_g
// (scalar LDS reads, H recomputed 16x). New structure: 256 blocks (i,j),
// H once per block, phase-2 register-tiled mini-GEMM with broadcast float4
// c2 reads + padded LDS (stride 20) + coalesced packed bf16 stores.
// gemm_bb (m97 structure, 822 TF = structural plateau) unchanged.
//   d_ws: [0,32MB) G bf16 [4096,4096]; [32MB,96MB) x bf16 [8192,4096].
// ---------------------------------------------------------------------------

typedef short bf16x8 __attribute__((ext_vector_type(8)));
typedef float f32x4 __attribute__((ext_vector_type(4)));

__device__ __forceinline__ unsigned short f2bf_rne(float f) {
  union { float f; unsigned int i; } v;
  v.f = f;
  unsigned int r = v.i + 0x7FFFu + ((v.i >> 16) & 1u);
  return (unsigned short)(r >> 16);
}

__device__ __forceinline__ unsigned int pk2bf_rne(float lo, float hi) {
  return (unsigned int)f2bf_rne(lo) | ((unsigned int)f2bf_rne(hi) << 16);
}

__device__ __forceinline__ unsigned int pk2bf_trunc(float lo, float hi) {
  union { float f; unsigned int u; } a, b;
  a.f = lo; b.f = hi;
  return (b.u & 0xFFFF0000u) | (a.u >> 16);
}

__device__ __forceinline__ void gl2lds16(const void* g, void* l) {
  __builtin_amdgcn_global_load_lds(
      (__attribute__((address_space(1))) void*)g,
      (__attribute__((address_space(3))) void*)l, 16u, 0, 0u);
}

// ---------------------------------------------------------------------------
// x fp32 -> bf16 (RNE), 8 elems/thread.
// ---------------------------------------------------------------------------
__global__ __launch_bounds__(256) void cvt_x(const float* __restrict__ x,
                                             unsigned short* __restrict__ xb) {
  const size_t t = (size_t)blockIdx.x * 256 + threadIdx.x;
  const float4 a0 = *(const float4*)(x + t * 8);
  const float4 a1 = *(const float4*)(x + t * 8 + 4);
  uint4 w = {pk2bf_rne(a0.x, a0.y), pk2bf_rne(a0.z, a0.w),
             pk2bf_rne(a1.x, a1.y), pk2bf_rne(a1.z, a1.w)};
  *(uint4*)(xb + t * 8) = w;
}

// ---------------------------------------------------------------------------
// build_g v2. Block = (i,j), 256 blocks, 256 threads (4 waves).
// G[(i,j,k)][(n,m,o)] = sum_c H[(n,m),c] * c2[c,k,o],
// H[(n,m),c] = sum_b c0[i,n,b] * c1[b,j,m,c].
// Phase 1: thread t computes H row t (vectorized, padded stride-20 LDS).
// Phase 2: wave w owns k in [4w,4w+4); lane l owns H rows {l,l+64,l+128,
// l+192} in 64 VGPRs; c2 read as broadcast float4 (conflict-free);
// output packed bf16, 2x uint4 per (row,k) — contiguous 512B/16 lanes.
// ---------------------------------------------------------------------------
__global__ __launch_bounds__(256, 1) void build_g(
    const float* __restrict__ core0,   // [1,16,16,16] (i,n,b)
    const float* __restrict__ core1,   // [16,16,16,16] (b,j,m,c)
    const float* __restrict__ core2,   // [16,16,16,1]  (c,k,o)
    unsigned short* __restrict__ G) {  // [4096,4096] bf16
  __shared__ float c0s[256];       // [n*16+b]
  __shared__ float c1s[16 * 320];  // [b][m*20+c]  (row stride 20: bank-safe)
  __shared__ float c2s[4096];      // [c*256+k*16+o]
  __shared__ float Hs[256 * 20];   // [nm*20+c]    (stride 20)
  const int t = threadIdx.x;
  const int blk = blockIdx.x;  // i*16 + j
  const int i = blk >> 4, j = blk & 15;

  // ---- stage (coalesced global loads) ----
  c0s[t] = core0[i * 256 + t];
  {
    const int m = t >> 4, c = t & 15;
#pragma unroll
    for (int b = 0; b < 16; b++)
      c1s[b * 320 + m * 20 + c] = core1[b * 4096 + j * 256 + t];
  }
#pragma unroll
  for (int q = 0; q < 16; q++) c2s[q * 256 + t] = core2[q * 256 + t];
  __syncthreads();

  // ---- phase 1: H row t = (n,m) ----
  {
    const int n = t >> 4, m = t & 15;
    f32x4 hv0 = {0.f, 0.f, 0.f, 0.f}, hv1 = hv0, hv2 = hv0, hv3 = hv0;
#pragma unroll
    for (int b = 0; b < 16; b++) {
      const float a = c0s[n * 16 + b];
      const f32x4* p = (const f32x4*)&c1s[b * 320 + m * 20];
      hv0 += a * p[0];
      hv1 += a * p[1];
      hv2 += a * p[2];
      hv3 += a * p[3];
    }
    f32x4* hp = (f32x4*)&Hs[t * 20];
    hp[0] = hv0; hp[1] = hv1; hp[2] = hv2; hp[3] = hv3;
  }
  __syncthreads();

  // ---- phase 2 ----
  const int w = t >> 6, l = t & 63;
  f32x4 hr[4][4];  // [q][c/4] — rows l+64q, 16 c each
#pragma unroll
  for (int q = 0; q < 4; q++) {
    const f32x4* hp = (const f32x4*)&Hs[(l + 64 * q) * 20];
#pragma unroll
    for (int d = 0; d < 4; d++) hr[q][d] = hp[d];
  }

#pragma unroll
  for (int kk = 0; kk < 4; kk++) {
    const int k = w * 4 + kk;
    f32x4 acc[4][4];  // [q][o/4]
    const f32x4 zero = {0.f, 0.f, 0.f, 0.f};
#pragma unroll
    for (int q = 0; q < 4; q++)
#pragma unroll
      for (int d = 0; d < 4; d++) acc[q][d] = zero;

#pragma unroll
    for (int c = 0; c < 16; c++) {
      const f32x4* cp = (const f32x4*)&c2s[c * 256 + k * 16];  // broadcast
      const f32x4 cv0 = cp[0], cv1 = cp[1], cv2 = cp[2], cv3 = cp[3];
#pragma unroll
      for (int q = 0; q < 4; q++) {
        const float hqc = hr[q][c >> 2][c & 3];
        acc[q][0] += hqc * cv0;
        acc[q][1] += hqc * cv1;
        acc[q][2] += hqc * cv2;
        acc[q][3] += hqc * cv3;
      }
    }

    const size_t rowbase = (size_t)(blk * 16 + k) * 4096;
#pragma unroll
    for (int q = 0; q < 4; q++) {
      unsigned int u[8];
#pragma unroll
      for (int d = 0; d < 8; d++)
        u[d] = pk2bf_rne(acc[q][d >> 1][(d & 1) * 2],
                         acc[q][d >> 1][(d & 1) * 2 + 1]);
      uint4* gp = (uint4*)&G[rowbase + (size_t)(l + 64 * q) * 16];
      uint4 s0 = {u[0], u[1], u[2], u[3]};
      uint4 s1 = {u[4], u[5], u[6], u[7]};
      gp[0] = s0;
      gp[1] = s1;
    }
  }
}

// ---------------------------------------------------------------------------
// GEMM (m97 structure): C[M,N] = A[M,K] * Bt[N,K]^T + bias. A,Bt bf16 async-
// DMA staged; fp32 accumulate/out. 822 TF measured (structural plateau).
// ---------------------------------------------------------------------------
constexpr int Mdim = 8192, Ndim = 4096, Kdim = 4096;

__global__ __launch_bounds__(256, 4) void gemm_bb(
    const unsigned short* __restrict__ A,     // [M,K] bf16
    const unsigned short* __restrict__ Bt,    // [N,K] bf16
    const float* __restrict__ bias,           // [N]
    float* __restrict__ C) {                  // [M,N] fp32
  __shared__ __align__(16) unsigned short lA[128 * 32];
  __shared__ __align__(16) unsigned short lB[128 * 32];
  const int tid = threadIdx.x, lane = tid & 63, wave = tid >> 6;
  const int bm0 = blockIdx.y * 128, bn0 = blockIdx.x * 128;
  const int wm = wave >> 1, wn = wave & 1;

  const int srow = lane >> 2, scol = (lane & 3) * 8;
  const unsigned short* Ag = A + (size_t)(bm0 + wave * 32 + srow) * Kdim + scol;
  const unsigned short* Bg = Bt + (size_t)(bn0 + wave * 32 + srow) * Kdim + scol;
  unsigned short* lAp = &lA[wave * 32 * 32 + lane * 8];
  unsigned short* lBp = &lB[wave * 32 * 32 + lane * 8];

  f32x4 acc[4][4];
  const f32x4 zero = {0.f, 0.f, 0.f, 0.f};
#pragma unroll
  for (int a = 0; a < 4; a++)
#pragma unroll
    for (int b = 0; b < 4; b++) acc[a][b] = zero;

  const int row = lane & 15, quad = lane >> 4;

  for (int k0 = 0; k0 < Kdim; k0 += 32) {
    __syncthreads();
    gl2lds16(Ag + k0, lAp);
    gl2lds16(Ag + k0 + 16 * Kdim, lAp + 16 * 32);
    gl2lds16(Bg + k0, lBp);
    gl2lds16(Bg + k0 + 16 * Kdim, lBp + 16 * 32);
    __syncthreads();

    bf16x8 af[4], bfv[4];
#pragma unroll
    for (int mi = 0; mi < 4; mi++)
      af[mi] = *(const bf16x8*)&lA[(wm * 64 + mi * 16 + row) * 32 + quad * 8];
#pragma unroll
    for (int ni = 0; ni < 4; ni++)
      bfv[ni] = *(const bf16x8*)&lB[(wn * 64 + ni * 16 + row) * 32 + quad * 8];
#pragma unroll
    for (int mi = 0; mi < 4; mi++)
#pragma unroll
      for (int ni = 0; ni < 4; ni++)
        acc[mi][ni] = __builtin_amdgcn_mfma_f32_16x16x32_bf16(
            af[mi], bfv[ni], acc[mi][ni], 0, 0, 0);
  }

#pragma unroll
  for (int ni = 0; ni < 4; ni++) {
    const int n = bn0 + wn * 64 + ni * 16 + row;
    const float bv = bias[n];
#pragma unroll
    for (int mi = 0; mi < 4; mi++) {
      const int mbase = bm0 + wm * 64 + mi * 16 + quad * 4;
#pragma unroll
      for (int r = 0; r < 4; r++)
        C[(size_t)(mbase + r) * Ndim + n] = acc[mi][ni][r] + bv;
    }
  }
}

// ---------------------------------------------------------------------------
// Fallback GEMM (only if ws_size < 96 MB): A fp32 packed in-loop (R1, 500us).
// ---------------------------------------------------------------------------
__global__ __launch_bounds__(256, 3) void gemm_pack(
    const float* __restrict__ A, const unsigned short* __restrict__ Bt,
    const float* __restrict__ bias, float* __restrict__ C) {
  __shared__ __align__(16) unsigned short lA[128 * 32];
  __shared__ __align__(16) unsigned short lB[128 * 32];
  const int tid = threadIdx.x, lane = tid & 63, wave = tid >> 6;
  const int bm0 = blockIdx.y * 128, bn0 = blockIdx.x * 128;
  const int wm = wave >> 1, wn = wave & 1;
  const int srow = lane >> 2, scol = (lane & 3) * 8;
  const unsigned short* Bg = Bt + (size_t)(bn0 + wave * 32 + srow) * Kdim + scol;
  unsigned short* lBp = &lB[wave * 32 * 32 + lane * 8];
  const int arow = wave * 16 + (lane >> 2);
  const int acol = (lane & 3) * 8;
  const float* Ag0 = A + (size_t)(bm0 + arow) * Kdim + acol;
  const float* Ag1 = Ag0 + (size_t)64 * Kdim;
  uint4* lAw0 = (uint4*)&lA[tid * 8];
  uint4* lAw1 = (uint4*)&lA[2048 + tid * 8];

  f32x4 acc[4][4];
  const f32x4 zero = {0.f, 0.f, 0.f, 0.f};
#pragma unroll
  for (int a = 0; a < 4; a++)
#pragma unroll
    for (int b = 0; b < 4; b++) acc[a][b] = zero;
  const int row = lane & 15, quad = lane >> 4;

  for (int k0 = 0; k0 < Kdim; k0 += 32) {
    __syncthreads();
    gl2lds16(Bg + k0, lBp);
    gl2lds16(Bg + k0 + 16 * Kdim, lBp + 16 * 32);
    float4 a0 = *(const float4*)(Ag0 + k0);
    float4 a1 = *(const float4*)(Ag0 + k0 + 4);
    float4 a2 = *(const float4*)(Ag1 + k0);
    float4 a3 = *(const float4*)(Ag1 + k0 + 4);
    uint4 w0 = {pk2bf_trunc(a0.x, a0.y), pk2bf_trunc(a0.z, a0.w),
                pk2bf_trunc(a1.x, a1.y), pk2bf_trunc(a1.z, a1.w)};
    uint4 w1 = {pk2bf_trunc(a2.x, a2.y), pk2bf_trunc(a2.z, a2.w),
                pk2bf_trunc(a3.x, a3.y), pk2bf_trunc(a3.z, a3.w)};
    *lAw0 = w0;
    *lAw1 = w1;
    __syncthreads();

    bf16x8 af[4], bfv[4];
#pragma unroll
    for (int mi = 0; mi < 4; mi++)
      af[mi] = *(const bf16x8*)&lA[(wm * 64 + mi * 16 + row) * 32 + quad * 8];
#pragma unroll
    for (int ni = 0; ni < 4; ni++)
      bfv[ni] = *(const bf16x8*)&lB[(wn * 64 + ni * 16 + row) * 32 + quad * 8];
#pragma unroll
    for (int mi = 0; mi < 4; mi++)
#pragma unroll
      for (int ni = 0; ni < 4; ni++)
        acc[mi][ni] = __builtin_amdgcn_mfma_f32_16x16x32_bf16(
            af[mi], bfv[ni], acc[mi][ni], 0, 0, 0);
  }
#pragma unroll
  for (int ni = 0; ni < 4; ni++) {
    const int n = bn0 + wn * 64 + ni * 16 + row;
    const float bv = bias[n];
#pragma unroll
    for (int mi = 0; mi < 4; mi++) {
      const int mbase = bm0 + wm * 64 + mi * 16 + quad * 4;
#pragma unroll
      for (int r = 0; r < 4; r++)
        C[(size_t)(mbase + r) * Ndim + n] = acc[mi][ni][r] + bv;
    }
  }
}

// ---------------------------------------------------------------------------
extern "C" void kernel_launch(void* const* d_in, const int* in_sizes, int n_in,
                              void* d_out, int out_size, void* d_ws,
                              size_t ws_size, hipStream_t stream) {
  const float* x = (const float*)d_in[0];
  const float* core0 = (const float*)d_in[1];
  const float* core1 = (const float*)d_in[2];
  const float* core2 = (const float*)d_in[3];
  const float* bias = (const float*)d_in[4];
  float* out = (float*)d_out;

  unsigned short* G = (unsigned short*)d_ws;
  const size_t G_BYTES = (size_t)4096 * 4096 * 2;
  const size_t X_BYTES = (size_t)Mdim * Kdim * 2;

  build_g<<<256, 256, 0, stream>>>(core0, core1, core2, G);
  dim3 grid(Ndim / 128, Mdim / 128);

  if (ws_size >= G_BYTES + X_BYTES) {
    unsigned short* Xb = (unsigned short*)((char*)d_ws + G_BYTES);
    cvt_x<<<(Mdim * Kdim) / (256 * 8), 256, 0, stream>>>(x, Xb);
    gemm_bb<<<grid, 256, 0, stream>>>(Xb, G, bias, out);
  } else {
    gemm_pack<<<grid, 256, 0, stream>>>(x, G, bias, out);
  }
}